// Round 2
// baseline (314.566 us; speedup 1.0000x reference)
//
#include <hip/hip_runtime.h>
#include <cstdint>
#include <cstddef>

// Problem constants (from reference): B=16, S=4096, C=512, A=0.5
#define PB 16
#define PS 4096
#define PC 512

// ---------------------------------------------------------------------------
// K0: zero the accumulators that later kernels atomicAdd into.
// ---------------------------------------------------------------------------
__global__ __launch_bounds__(256) void k0_init(int* __restrict__ nCnt,
                                               float* __restrict__ colsum,
                                               float* __restrict__ Lsum,
                                               float* __restrict__ acc) {
    int i = blockIdx.x * 256 + threadIdx.x;
    if (i < PB * PC) { nCnt[i] = 0; colsum[i] = 0.0f; }
    if (i < PB) Lsum[i] = 0.0f;
    if (i < 2) acc[i] = 0.0f;
}

// ---------------------------------------------------------------------------
// K1: one wave per row (b,s): argmax, logsumexp, target histogram, column
// sums (LDS partial -> atomics), per-batch lse sum.
// Grid: 2048 blocks (CH=128 chunks/batch, 32 rows/block) -> 8 blocks/CU,
// 32 waves/CU (full occupancy; was 512 blocks -> 19% occupancy, latency-bound).
// ---------------------------------------------------------------------------
__global__ __launch_bounds__(256) void k1_rows(const float* __restrict__ pred,
                                               const int* __restrict__ target,
                                               int* __restrict__ am,
                                               float* __restrict__ lse,
                                               int* __restrict__ nCnt,
                                               float* __restrict__ colsum,
                                               float* __restrict__ Lsum) {
    const int CH = 128;           // chunks per batch
    const int RPB = PS / CH;      // 32 rows per block
    int b = blockIdx.x / CH;
    int chunk = blockIdx.x % CH;
    int w = threadIdx.x >> 6;     // wave id in block (0..3)
    int l = threadIdx.x & 63;     // lane

    float cs0 = 0.f, cs1 = 0.f, cs2 = 0.f, cs3 = 0.f;
    float cs4 = 0.f, cs5 = 0.f, cs6 = 0.f, cs7 = 0.f;
    float lseAcc = 0.f;

    __shared__ float lds[4][PC];

    #pragma unroll
    for (int i = 0; i < RPB / 4; ++i) {
        int row = chunk * RPB + i * 4 + w;
        size_t base = ((size_t)(b * PS + row)) * PC;
        const float4* p = (const float4*)(pred + base);
        float4 v0 = p[l];
        float4 v1 = p[64 + l];

        // lane-local argmax over 8 elements, earliest-column preference
        float bv = v0.x; int bi = 4 * l;
        if (v0.y > bv) { bv = v0.y; bi = 4 * l + 1; }
        if (v0.z > bv) { bv = v0.z; bi = 4 * l + 2; }
        if (v0.w > bv) { bv = v0.w; bi = 4 * l + 3; }
        if (v1.x > bv) { bv = v1.x; bi = 256 + 4 * l; }
        if (v1.y > bv) { bv = v1.y; bi = 256 + 4 * l + 1; }
        if (v1.z > bv) { bv = v1.z; bi = 256 + 4 * l + 2; }
        if (v1.w > bv) { bv = v1.w; bi = 256 + 4 * l + 3; }

        // wave butterfly: (max value, min index on tie) is associative+commutative
        #pragma unroll
        for (int off = 1; off < 64; off <<= 1) {
            float ov = __shfl_xor(bv, off, 64);
            int   oi = __shfl_xor(bi, off, 64);
            if (ov > bv || (ov == bv && oi < bi)) { bv = ov; bi = oi; }
        }
        // bv is now the row max; bi the first argmax index.

        float se = expf(v0.x - bv) + expf(v0.y - bv) + expf(v0.z - bv) + expf(v0.w - bv)
                 + expf(v1.x - bv) + expf(v1.y - bv) + expf(v1.z - bv) + expf(v1.w - bv);
        #pragma unroll
        for (int off = 1; off < 64; off <<= 1) se += __shfl_xor(se, off, 64);
        float l_row = bv + logf(se);

        if (l == 0) {
            int gidx = b * PS + row;
            lse[gidx] = l_row;
            am[gidx] = bi;
            int t = target[gidx];
            atomicAdd(&nCnt[b * PC + t], 1);
            lseAcc += l_row;
        }

        cs0 += v0.x; cs1 += v0.y; cs2 += v0.z; cs3 += v0.w;
        cs4 += v1.x; cs5 += v1.y; cs6 += v1.z; cs7 += v1.w;
    }

    if (l == 0) atomicAdd(&Lsum[b], lseAcc);

    // column sums: each wave owns its LDS slice (no intra-wave column overlap)
    lds[w][4 * l + 0] = cs0; lds[w][4 * l + 1] = cs1;
    lds[w][4 * l + 2] = cs2; lds[w][4 * l + 3] = cs3;
    lds[w][256 + 4 * l + 0] = cs4; lds[w][256 + 4 * l + 1] = cs5;
    lds[w][256 + 4 * l + 2] = cs6; lds[w][256 + 4 * l + 3] = cs7;
    __syncthreads();
    for (int c = threadIdx.x; c < PC; c += 256) {
        float s = lds[0][c] + lds[1][c] + lds[2][c] + lds[3][c];
        atomicAdd(&colsum[b * PC + c], s);
    }
}

// ---------------------------------------------------------------------------
// K2: per-batch exclusive prefix sum of nCnt -> bucket offsets + cursor copy.
// ---------------------------------------------------------------------------
__global__ __launch_bounds__(512) void k2_scan(const int* __restrict__ nCnt,
                                               int* __restrict__ offs,
                                               int* __restrict__ cursor) {
    int b = blockIdx.x;
    int t = threadIdx.x;
    __shared__ int sc[PC];
    int x = nCnt[b * PC + t];
    sc[t] = x;
    __syncthreads();
    for (int off = 1; off < PC; off <<= 1) {
        int v = (t >= off) ? sc[t - off] : 0;
        __syncthreads();
        sc[t] += v;
        __syncthreads();
    }
    int g = b * PS + (sc[t] - x);   // global exclusive offset
    offs[b * PC + t] = g;
    cursor[b * PC + t] = g;
}

// ---------------------------------------------------------------------------
// K3: counting-sort scatter into per-(b,target) buckets. Entry packs both the
// position s (12 bits) and its argmax class am (9 bits): s | (am<<12).
// This removes a dependent-gather level from K4.
// ---------------------------------------------------------------------------
__global__ __launch_bounds__(256) void k3_scatter(const int* __restrict__ target,
                                                  const int* __restrict__ am,
                                                  int* __restrict__ cursor,
                                                  int* __restrict__ bucket) {
    int gid = blockIdx.x * 256 + threadIdx.x;   // < B*S
    int b = gid >> 12;
    int s = gid & (PS - 1);
    int t = target[gid];
    int a = am[gid];
    int pos = atomicAdd(&cursor[b * PC + t], 1);
    bucket[pos] = s | (a << 12);
}

// ---------------------------------------------------------------------------
// K4: one thread per (b,t) pair. Mode m of am over the bucket (tie -> smallest
// class), then eq_sum / ne_sum / val per reference; wave-reduce into acc.
// 128 blocks x 64 threads spreads the 8192 pairs over 128 CUs.
// ---------------------------------------------------------------------------
__global__ __launch_bounds__(64) void k4_pairs(const float* __restrict__ pred,
                                               const int* __restrict__ nCnt,
                                               const int* __restrict__ offs,
                                               const int* __restrict__ bucket,
                                               const float* __restrict__ lse,
                                               const float* __restrict__ colsum,
                                               const float* __restrict__ Lsum,
                                               float* __restrict__ acc) {
    __shared__ int cache[64][33];   // +1 pad: conflict-free
    int pair = blockIdx.x * 64 + threadIdx.x;   // < B*C
    int b = pair >> 9;
    int k = nCnt[pair];
    int start = offs[pair];

    float val = 0.f;
    int keep = 0;

    if (k > 0) {
        int kc = (k < 32) ? k : 32;
        for (int i = 0; i < kc; ++i)
            cache[threadIdx.x][i] = bucket[start + i];   // independent loads

        // mode with tie -> smallest class value
        int bc = 0, bvv = 0;
        if (k <= 32) {
            for (int i = 0; i < k; ++i) {
                int v = cache[threadIdx.x][i] >> 12;
                int c = 0;
                for (int j = 0; j < k; ++j) c += ((cache[threadIdx.x][j] >> 12) == v) ? 1 : 0;
                if (c > bc || (c == bc && v < bvv)) { bc = c; bvv = v; }
            }
        } else {
            for (int i = 0; i < k; ++i) {
                int v = bucket[start + i] >> 12;
                int c = 0;
                for (int j = 0; j < k; ++j)
                    c += ((bucket[start + j] >> 12) == v) ? 1 : 0;
                if (c > bc || (c == bc && v < bvv)) { bc = c; bvv = v; }
            }
        }
        int m = bvv;

        float lseSum = 0.f, ep = 0.f;
        for (int i = 0; i < k; ++i) {
            int e = (i < 32) ? cache[threadIdx.x][i] : bucket[start + i];
            int s = e & (PS - 1);
            lseSum += lse[(b << 12) + s];
            ep += pred[(((size_t)(b << 12)) + s) * PC + m];
        }
        float eq_sum = lseSum - ep;
        float total_term = Lsum[b] - colsum[(b << 9) + m];
        float ne_sum = total_term - eq_sum;
        float nf = (float)k;
        float eq_loss = eq_sum / fmaxf(nf, 1.0f);
        float ne_mean = ne_sum / fmaxf((float)PS - nf, 1.0f);
        float ne_loss = 1.0f / ((ne_mean != 0.0f) ? ne_mean : 1.0f);
        val = 0.5f * eq_loss + 0.5f * ne_loss;
        keep = (val != 0.0f) ? 1 : 0;
    }

    float vs = keep ? val : 0.0f;
    float ks = (float)keep;
    #pragma unroll
    for (int off = 1; off < 64; off <<= 1) {
        vs += __shfl_xor(vs, off, 64);
        ks += __shfl_xor(ks, off, 64);
    }
    if ((threadIdx.x & 63) == 0) {
        atomicAdd(&acc[0], vs);
        atomicAdd(&acc[1], ks);
    }
}

// ---------------------------------------------------------------------------
// K5: final scalar.
// ---------------------------------------------------------------------------
__global__ void k5_final(const float* __restrict__ acc, float* __restrict__ out) {
    if (threadIdx.x == 0 && blockIdx.x == 0)
        out[0] = acc[0] / fmaxf(acc[1], 1.0f);
}

extern "C" void kernel_launch(void* const* d_in, const int* in_sizes, int n_in,
                              void* d_out, int out_size, void* d_ws, size_t ws_size,
                              hipStream_t stream) {
    const float* pred = (const float*)d_in[0];   // (B,S,C) f32
    const int* target = (const int*)d_in[1];     // (B,S) int
    float* out = (float*)d_out;

    char* w = (char*)d_ws;
    int*   am     = (int*)(w + 0);          // B*S ints   = 256 KiB
    float* lse    = (float*)(w + 262144);   // B*S floats = 256 KiB
    int*   bucket = (int*)(w + 524288);     // B*S ints   = 256 KiB
    int*   nCnt   = (int*)(w + 786432);     // B*C ints   =  32 KiB
    int*   offs   = (int*)(w + 819200);     // B*C ints
    int*   cursor = (int*)(w + 851968);     // B*C ints
    float* colsum = (float*)(w + 884736);   // B*C floats
    float* Lsum   = (float*)(w + 917504);   // B floats
    float* acc    = (float*)(w + 917568);   // 2 floats

    k0_init<<<32, 256, 0, stream>>>(nCnt, colsum, Lsum, acc);
    k1_rows<<<PB * 128, 256, 0, stream>>>(pred, target, am, lse, nCnt, colsum, Lsum);
    k2_scan<<<PB, 512, 0, stream>>>(nCnt, offs, cursor);
    k3_scatter<<<(PB * PS) / 256, 256, 0, stream>>>(target, am, cursor, bucket);
    k4_pairs<<<(PB * PC) / 64, 64, 0, stream>>>(pred, nCnt, offs, bucket, lse,
                                                colsum, Lsum, acc);
    k5_final<<<1, 64, 0, stream>>>(acc, out);
}

// Round 3
// 248.560 us; speedup vs baseline: 1.2656x; 1.2656x over previous
//
#include <hip/hip_runtime.h>
#include <cstdint>
#include <cstddef>

// Problem constants (from reference): B=16, S=4096, C=512, A=0.5
#define PB 16
#define PS 4096
#define PC 512

#define RPB 128        // rows per block in k1
#define PANEL 32       // columns per panel
#define NPANEL (PC / PANEL)
#define LSTRIDE 33     // +1 pad: <=2-way bank aliasing (free per m136)

// ---------------------------------------------------------------------------
// K0: zero the accumulators k1 atomicAdds into.
// ---------------------------------------------------------------------------
__global__ __launch_bounds__(256) void k0_init(int* __restrict__ nCnt,
                                               float* __restrict__ colsum,
                                               float* __restrict__ Lsum) {
    int i = blockIdx.x * 256 + threadIdx.x;
    if (i < PB * PC) { nCnt[i] = 0; colsum[i] = 0.0f; }
    if (i < PB) Lsum[i] = 0.0f;
}

// ---------------------------------------------------------------------------
// K1: LDS-staged streaming pass over predicted.
// Block: 256 threads, 128 rows, 16 panels x 32 cols, double-buffered LDS.
// Thread t owns half-row (row = t>>1, col half = t&1) and keeps online
// softmax state (max, first-argmax, exp-sum) in registers -> no cross-lane
// ops in the hot loop (the R1/R2 butterfly chains were the latency wall).
// Column sums: per-panel LDS column sub-phase -> colLDS -> 512 global atomics.
// ---------------------------------------------------------------------------
__global__ __launch_bounds__(256) void k1_rows(const float* __restrict__ pred,
                                               const int* __restrict__ target,
                                               int* __restrict__ am,
                                               float* __restrict__ lse,
                                               int* __restrict__ nCnt,
                                               float* __restrict__ colsum,
                                               float* __restrict__ Lsum) {
    __shared__ float tile[2][RPB * LSTRIDE];   // 2*128*33*4 = 33792 B
    __shared__ float colLDS[PC];               // 2048 B

    const int t = threadIdx.x;
    const int rowBase = blockIdx.x * RPB;      // global row of this block
    const int b = rowBase >> 12;               // PS = 4096
    const float* base = pred + (size_t)rowBase * PC;

    colLDS[t] = 0.0f; colLDS[t + 256] = 0.0f;

    // Loader mapping: thread t owns float4 slots g = j*256+t (j=0..3) of each
    // 128x32 panel: r = g>>3 (row), c4 = g&7 (float4 within panel row).
    const float* pj[4];
    int ldsOff[4];
    #pragma unroll
    for (int j = 0; j < 4; ++j) {
        int g = j * 256 + t;
        int r = g >> 3, c4 = g & 7;
        pj[j] = base + (size_t)r * PC + 4 * c4;
        ldsOff[j] = r * LSTRIDE + 4 * c4;
    }

    float4 reg[4];
    #pragma unroll
    for (int j = 0; j < 4; ++j) reg[j] = *(const float4*)(pj[j]);  // panel 0

    // per-thread online softmax state over its half-row
    const int rt = t >> 1;      // row within block
    const int h = t & 1;        // column half
    float mval = -3.4e38f;
    float ssum = 0.0f;
    int midx = 0;

    for (int p = 0; p < NPANEL; ++p) {
        float* tb = tile[p & 1];
        #pragma unroll
        for (int j = 0; j < 4; ++j) {
            float* d = tb + ldsOff[j];
            d[0] = reg[j].x; d[1] = reg[j].y; d[2] = reg[j].z; d[3] = reg[j].w;
        }
        __syncthreads();

        if (p + 1 < NPANEL) {
            #pragma unroll
            for (int j = 0; j < 4; ++j)
                reg[j] = *(const float4*)(pj[j] + (p + 1) * PANEL);   // prefetch
        }

        // row scan: 16 elements of this thread's half-row
        const int c0 = p * PANEL;
        const float* rowp = tb + rt * LSTRIDE + 16 * h;
        #pragma unroll
        for (int i = 0; i < 16; ++i) {
            float v = rowp[i];
            if (v > mval) {
                ssum = ssum * __expf(mval - v) + 1.0f;
                mval = v;
                midx = c0 + 16 * h + i;          // first max: strict >
            } else {
                ssum += __expf(v - mval);
            }
        }

        // column partial sums: thread t sums 16 rows of panel-col (t&31)
        {
            int cl = t & 31, g2 = t >> 5;
            const float* colp = tb + (g2 * 16) * LSTRIDE + cl;
            float part = 0.0f;
            #pragma unroll
            for (int r = 0; r < 16; ++r) part += colp[r * LSTRIDE];
            atomicAdd(&colLDS[c0 + cl], part);   // 8-way LDS atomic, cheap
        }
        // single barrier per panel: p's reads precede (p+1)'s barrier in
        // program order, which precedes (p+2)'s overwrite of this buffer.
    }

    // combine the two half-row states (lanes t, t^1 are in the same wave)
    float om = __shfl_xor(mval, 1, 64);
    float os = __shfl_xor(ssum, 1, 64);
    int   oi = __shfl_xor(midx, 1, 64);
    float M = fmaxf(mval, om);
    int IDX = (om > mval || (om == mval && oi < midx)) ? oi : midx;
    float S = ssum * __expf(mval - M) + os * __expf(om - M);
    float lse_v = M + __logf(S);

    if (h == 0) {
        int grow = rowBase + rt;
        lse[grow] = lse_v;
        am[grow] = IDX;
        int tg = target[grow];
        atomicAdd(&nCnt[(b << 9) + tg], 1);
    }

    // per-batch lse sum: wave reduce then one atomic per wave
    float lv = (h == 0) ? lse_v : 0.0f;
    #pragma unroll
    for (int off = 1; off < 64; off <<= 1) lv += __shfl_xor(lv, off, 64);
    if ((t & 63) == 0) atomicAdd(&Lsum[b], lv);

    __syncthreads();
    atomicAdd(&colsum[(b << 9) + t], colLDS[t]);
    atomicAdd(&colsum[(b << 9) + t + 256], colLDS[t + 256]);
}

// ---------------------------------------------------------------------------
// K23: fused per-batch scan + scatter. One block (512 threads) per batch.
// LDS cursor -> no global cursor array, no global atomics. Block 0 also
// zeroes acc/done for K45.
// ---------------------------------------------------------------------------
__global__ __launch_bounds__(512) void k23(const int* __restrict__ nCnt,
                                           const int* __restrict__ target,
                                           const int* __restrict__ am,
                                           int* __restrict__ offs,
                                           int* __restrict__ bucket,
                                           float* __restrict__ acc,
                                           int* __restrict__ done) {
    int b = blockIdx.x;
    int t = threadIdx.x;
    __shared__ int sc[PC];
    __shared__ int cur[PC];
    int x = nCnt[(b << 9) + t];
    sc[t] = x;
    __syncthreads();
    for (int off = 1; off < PC; off <<= 1) {
        int v = (t >= off) ? sc[t - off] : 0;
        __syncthreads();
        sc[t] += v;
        __syncthreads();
    }
    int g = (b << 12) + (sc[t] - x);   // global exclusive offset
    offs[(b << 9) + t] = g;
    cur[t] = g;
    if (b == 0 && t < 3) {
        if (t < 2) acc[t] = 0.0f;
        else *done = 0;
    }
    __syncthreads();
    for (int i = t; i < PS; i += 512) {
        int gi = (b << 12) + i;
        int tg = target[gi];
        int a = am[gi];
        int pos = atomicAdd(&cur[tg], 1);
        bucket[pos] = i | (a << 12);   // s in 12 bits, am class in high bits
    }
}

// ---------------------------------------------------------------------------
// K45: one thread per (b,t) pair; mode of am over the bucket (tie -> smallest
// class), eq/ne sums, val; wave-reduce into acc; last-done block writes out.
// ---------------------------------------------------------------------------
__global__ __launch_bounds__(64) void k45(const float* __restrict__ pred,
                                          const int* __restrict__ nCnt,
                                          const int* __restrict__ offs,
                                          const int* __restrict__ bucket,
                                          const float* __restrict__ lse,
                                          const float* __restrict__ colsum,
                                          const float* __restrict__ Lsum,
                                          float* __restrict__ acc,
                                          int* __restrict__ done,
                                          float* __restrict__ out) {
    __shared__ int cache[64][33];
    int pair = blockIdx.x * 64 + threadIdx.x;   // < B*C
    int b = pair >> 9;
    int k = nCnt[pair];
    int start = offs[pair];

    float val = 0.0f;
    int keep = 0;

    if (k > 0) {
        int kc = (k < 32) ? k : 32;
        for (int i = 0; i < kc; ++i)
            cache[threadIdx.x][i] = bucket[start + i];

        int bc = 0, bvv = 0;
        if (k <= 32) {
            for (int i = 0; i < k; ++i) {
                int v = cache[threadIdx.x][i] >> 12;
                int c = 0;
                for (int j = 0; j < k; ++j) c += ((cache[threadIdx.x][j] >> 12) == v) ? 1 : 0;
                if (c > bc || (c == bc && v < bvv)) { bc = c; bvv = v; }
            }
        } else {
            for (int i = 0; i < k; ++i) {
                int v = bucket[start + i] >> 12;
                int c = 0;
                for (int j = 0; j < k; ++j)
                    c += ((bucket[start + j] >> 12) == v) ? 1 : 0;
                if (c > bc || (c == bc && v < bvv)) { bc = c; bvv = v; }
            }
        }
        int m = bvv;

        float lseSum = 0.0f, ep = 0.0f;
        for (int i = 0; i < k; ++i) {
            int e = (i < 32) ? cache[threadIdx.x][i] : bucket[start + i];
            int s = e & (PS - 1);
            lseSum += lse[(b << 12) + s];
            ep += pred[(((size_t)(b << 12)) + s) * PC + m];
        }
        float eq_sum = lseSum - ep;
        float total_term = Lsum[b] - colsum[(b << 9) + m];
        float ne_sum = total_term - eq_sum;
        float nf = (float)k;
        float eq_loss = eq_sum / fmaxf(nf, 1.0f);
        float ne_mean = ne_sum / fmaxf((float)PS - nf, 1.0f);
        float ne_loss = 1.0f / ((ne_mean != 0.0f) ? ne_mean : 1.0f);
        val = 0.5f * eq_loss + 0.5f * ne_loss;
        keep = (val != 0.0f) ? 1 : 0;
    }

    float vs = keep ? val : 0.0f;
    float ks = (float)keep;
    #pragma unroll
    for (int off = 1; off < 64; off <<= 1) {
        vs += __shfl_xor(vs, off, 64);
        ks += __shfl_xor(ks, off, 64);
    }
    if (threadIdx.x == 0) {
        atomicAdd(&acc[0], vs);
        atomicAdd(&acc[1], ks);
        __threadfence();
        int d = atomicAdd(done, 1);
        if (d == (int)gridDim.x - 1) {
            __threadfence();
            float a0 = atomicAdd(&acc[0], 0.0f);   // coherent read via atomic path
            float a1 = atomicAdd(&acc[1], 0.0f);
            out[0] = a0 / fmaxf(a1, 1.0f);
        }
    }
}

extern "C" void kernel_launch(void* const* d_in, const int* in_sizes, int n_in,
                              void* d_out, int out_size, void* d_ws, size_t ws_size,
                              hipStream_t stream) {
    const float* pred = (const float*)d_in[0];   // (B,S,C) f32
    const int* target = (const int*)d_in[1];     // (B,S) int
    float* out = (float*)d_out;

    char* w = (char*)d_ws;
    int*   am     = (int*)(w + 0);          // B*S ints   = 256 KiB
    float* lse    = (float*)(w + 262144);   // B*S floats = 256 KiB
    int*   bucket = (int*)(w + 524288);     // B*S ints   = 256 KiB
    int*   nCnt   = (int*)(w + 786432);     // B*C ints   =  32 KiB
    int*   offs   = (int*)(w + 819200);     // B*C ints   =  32 KiB
    float* colsum = (float*)(w + 851968);   // B*C floats =  32 KiB
    float* Lsum   = (float*)(w + 884736);   // B floats
    float* acc    = (float*)(w + 884800);   // 2 floats
    int*   done   = (int*)(w + 884808);     // 1 int

    k0_init<<<32, 256, 0, stream>>>(nCnt, colsum, Lsum);
    k1_rows<<<(PB * PS) / RPB, 256, 0, stream>>>(pred, target, am, lse, nCnt, colsum, Lsum);
    k23<<<PB, 512, 0, stream>>>(nCnt, target, am, offs, bucket, acc, done);
    k45<<<(PB * PC) / 64, 64, 0, stream>>>(pred, nCnt, offs, bucket, lse,
                                           colsum, Lsum, acc, done, out);
}